// Round 4
// baseline (197.672 us; speedup 1.0000x reference)
//
#include <hip/hip_runtime.h>
#include <hip/hip_bf16.h>
#include <math.h>

#define B_   32
#define S_   512
#define D_   768
#define C_   128   // MAX_CHUNK_NUMBER
#define LCK  8     // MAX_CHUNK_LEN

#define MT    32   // rows per block
#define NSTG  72   // 6 z-panels * 12 k-steps
#define NZ    6    // 128-col panels
#define NK    12   // 64-k steps

typedef _Float16 half8_t __attribute__((ext_vector_type(8)));
typedef _Float16 half4_t __attribute__((ext_vector_type(4)));
typedef float    f32x4   __attribute__((ext_vector_type(4)));

__device__ __forceinline__ void gload16(const void* g, void* l) {
    __builtin_amdgcn_global_load_lds(
        (const __attribute__((address_space(1))) void*)g,
        (__attribute__((address_space(3))) void*)l, 16, 0, 0);
}

// ---------------- Kernel 1: scan (blocks 0..31) + Lc (block 32) ----------------
__global__ void scan_lc_kernel(const int* __restrict__ lens, int* __restrict__ starts,
                               int* __restrict__ Tb, const float* __restrict__ db,
                               const float* __restrict__ ab, const float* __restrict__ q,
                               float* __restrict__ Lc) {
    int t = threadIdx.x;
    if (blockIdx.x < 32) {
        int b = blockIdx.x;
        __shared__ int s[C_];
        if (t < C_) {
            int v = lens[b * C_ + t];
            s[t] = v;
            __syncthreads();
            for (int off = 1; off < C_; off <<= 1) {
                int add = (t >= off) ? s[t - off] : 0;
                __syncthreads();
                s[t] += add;
                __syncthreads();
            }
            starts[b * C_ + t] = s[t] - v;
            if (t == C_ - 1) Tb[b] = s[C_ - 1];
        } else {
            __syncthreads();
            for (int off = 1; off < C_; off <<= 1) { __syncthreads(); __syncthreads(); }
            // keep barrier counts matched for threads 128..255
        }
    } else {
        float p = 0.f;
        for (int e = t; e < D_; e += 256) p += tanhf(db[e] + ab[e]) * q[e];
        __shared__ float r[256];
        r[t] = p;
        __syncthreads();
        for (int off = 128; off > 0; off >>= 1) {
            if (t < off) r[t] += r[t + off];
            __syncthreads();
        }
        if (t == 0) *Lc = r[0];
    }
}

// ---------------- Kernel 1c: split W (fp32) -> Whi, Wlo (fp16) ----------------
__global__ __launch_bounds__(256) void wsplit_kernel(const float* __restrict__ W,
                                                     _Float16* __restrict__ hi,
                                                     _Float16* __restrict__ lo) {
    int i = (blockIdx.x * 256 + threadIdx.x) * 4;
    float4 w = *(const float4*)(W + i);
    float wf[4] = {w.x, w.y, w.z, w.w};
    half4_t h, l;
    #pragma unroll
    for (int j = 0; j < 4; ++j) {
        _Float16 hh = (_Float16)wf[j];
        h[j] = hh;
        l[j] = (_Float16)(wf[j] - (float)hh);
    }
    *(half4_t*)(hi + i) = h;
    *(half4_t*)(lo + i) = l;
}

// ---------------- Kernel 2: X-resident MFMA GEMM + tanh + q-dot ----------------
// logit[b,t] = sum_e q[e] * tanh( sum_d X[b,t,d]*W[e,d] + db[e]+ab[e] )
// X rows (32) live in REGISTERS as fp16 (A = 24 x half8). W hi/lo streams
// through 64 KB dbuf LDS via global_load_lds(16B) with pre-swizzled source
// (rule 21) and XOR-swizzled ds_read. Depth-2 pipeline, counted vmcnt(8).
// A-frag (16x16x32 f16): lane l holds A[l&15][(l>>4)*8+j]; B same on W rows.
// C/D: col=lane&15 (e), row=(lane>>4)*4+reg (m)  [verified in round-3 kernel]
__global__ __launch_bounds__(256, 1) void logits_mfma(
        const float* __restrict__ X,
        const _Float16* __restrict__ Whf, const _Float16* __restrict__ Wlf,
        const float* __restrict__ db, const float* __restrict__ ab,
        const float* __restrict__ q, const int* __restrict__ Tb,
        float* __restrict__ partial) {
    int b = blockIdx.y;
    int m0 = blockIdx.x * MT;
    if (m0 >= Tb[b]) return;

    // [buf][hl][row*64 + k] halves : 2*2*128*64*2B = 64 KB
    __shared__ _Float16 Ws[2][2][128 * 64];

    int tid = threadIdx.x;
    int lane = tid & 63, wid = tid >> 6;
    int wm = wid >> 1;         // row half: 16 rows
    int wn = wid & 1;          // col half: 64 of the 128-panel

    // ---- A prologue: 16 rows x 768 k, fp32 -> fp16 into registers ----
    half8_t A[NK][2];
    {
        const float* Xrow = X + ((size_t)(b * S_ + m0 + wm * 16 + (lane & 15))) * D_
                              + ((lane >> 4) * 8);
        #pragma unroll
        for (int ks = 0; ks < NK; ++ks) {
            #pragma unroll
            for (int sub = 0; sub < 2; ++sub) {
                const float* src = Xrow + ks * 64 + sub * 32;
                float4 f0 = *(const float4*)src;
                float4 f1 = *(const float4*)(src + 4);
                half8_t h;
                h[0] = (_Float16)f0.x; h[1] = (_Float16)f0.y;
                h[2] = (_Float16)f0.z; h[3] = (_Float16)f0.w;
                h[4] = (_Float16)f1.x; h[5] = (_Float16)f1.y;
                h[6] = (_Float16)f1.z; h[7] = (_Float16)f1.w;
                A[ks][sub] = h;
            }
        }
    }

    // ---- W stage issue: wave w covers rows [w*32, w*32+32) of hi and lo ----
    auto issue = [&](int zz, int kk, int buf) {
        int rb = wid * 32;
        #pragma unroll
        for (int hl = 0; hl < 2; ++hl) {
            const _Float16* Wsrc = hl ? Wlf : Whf;
            #pragma unroll
            for (int c = 0; c < 4; ++c) {
                int row = rb + c * 8 + (lane >> 3);
                int cg  = (lane & 7) ^ (row & 7);            // pre-swizzled source
                const _Float16* g = Wsrc + (size_t)(zz * 128 + row) * D_ + kk * 64 + cg * 8;
                _Float16* l = &Ws[buf][hl][(rb + c * 8) * 64];
                gload16(g, l);
            }
        }
    };

    float lsum[4] = {0.f, 0.f, 0.f, 0.f};

    issue(0, 0, 0);
    issue(0, 1, 1);
    asm volatile("s_waitcnt vmcnt(8)" ::: "memory");
    __builtin_amdgcn_sched_barrier(0);
    __builtin_amdgcn_s_barrier();

    for (int z = 0; z < NZ; ++z) {
        f32x4 acc[4];
        #pragma unroll
        for (int nt = 0; nt < 4; ++nt) acc[nt] = (f32x4)(0.0f);

        #pragma unroll
        for (int k = 0; k < NK; ++k) {
            const int buf = k & 1;
            // ---- compute stage (z,k): 16 MFMA from reg-A and LDS-B ----
            #pragma unroll
            for (int sub = 0; sub < 2; ++sub) {
                half8_t bh[4], bl[4];
                #pragma unroll
                for (int nt = 0; nt < 4; ++nt) {
                    int row = wn * 64 + nt * 16 + (lane & 15);
                    int cl  = (sub * 4 + (lane >> 4)) ^ (row & 7);
                    bh[nt] = *(const half8_t*)&Ws[buf][0][row * 64 + cl * 8];
                    bl[nt] = *(const half8_t*)&Ws[buf][1][row * 64 + cl * 8];
                }
                #pragma unroll
                for (int nt = 0; nt < 4; ++nt) {
                    acc[nt] = __builtin_amdgcn_mfma_f32_16x16x32_f16(A[k][sub], bh[nt], acc[nt], 0, 0, 0);
                    acc[nt] = __builtin_amdgcn_mfma_f32_16x16x32_f16(A[k][sub], bl[nt], acc[nt], 0, 0, 0);
                }
            }
            asm volatile("s_waitcnt lgkmcnt(0)" ::: "memory");
            __builtin_amdgcn_sched_barrier(0);
            __builtin_amdgcn_s_barrier();          // stage data consumed by all waves

            // ---- prefetch stage s+2 into the buffer just freed ----
            if (z * NK + k + 2 < NSTG) {
                if (k < NK - 2) issue(z, k + 2, buf);
                else            issue(z + 1, k - (NK - 2), buf);
                asm volatile("s_waitcnt vmcnt(8)" ::: "memory");   // s+1 ready
            } else {
                asm volatile("s_waitcnt vmcnt(0)" ::: "memory");   // drain tail
            }
            __builtin_amdgcn_sched_barrier(0);
            __builtin_amdgcn_s_barrier();
        }

        // ---- per-z epilogue: tanh + q-dot, accumulate per-row sums (regs only) ----
        #pragma unroll
        for (int nt = 0; nt < 4; ++nt) {
            int e = z * 128 + wn * 64 + nt * 16 + (lane & 15);
            float beta = db[e] + ab[e];
            float qe = q[e];
            #pragma unroll
            for (int r = 0; r < 4; ++r)
                lsum[r] += tanhf(acc[nt][r] + beta) * qe;
        }
    }

    // ---- final reduce: 16 col-lanes -> 1, then combine wn halves via LDS ----
    #pragma unroll
    for (int off = 1; off < 16; off <<= 1)
        #pragma unroll
        for (int r = 0; r < 4; ++r)
            lsum[r] += __shfl_xor(lsum[r], off, 64);

    __syncthreads();
    float* rsum = (float*)&Ws[0][0][0];   // [32 rows][2 wn]
    if ((lane & 15) == 0) {
        #pragma unroll
        for (int r = 0; r < 4; ++r)
            rsum[(wm * 16 + (lane >> 4) * 4 + r) * 2 + wn] = lsum[r];
    }
    __syncthreads();
    if (tid < MT)
        partial[(size_t)b * S_ + m0 + tid] = rsum[tid * 2] + rsum[tid * 2 + 1];
}

// ---------------- Kernel 3: per-chunk softmax + weighted sum + LayerNorm ----------------
__global__ __launch_bounds__(256) void chunk_kernel(
        const float* __restrict__ X, const int* __restrict__ lens,
        const int* __restrict__ starts, const float* __restrict__ partial,
        const float* __restrict__ Lcp, const float* __restrict__ lnw,
        const float* __restrict__ lnb, float* __restrict__ cf) {
    int c = blockIdx.x, b = blockIdx.y, tid = threadIdx.x;
    int len = lens[b * C_ + c];
    len = max(0, min(len, LCK));
    int start = starts[b * C_ + c];
    float Lc = *Lcp;

    // logits for all 8 slots (invalid slots = Lc)
    float lg[LCK];
    #pragma unroll
    for (int l = 0; l < LCK; ++l) {
        bool valid = l < len;
        int t = valid ? (start + l) : start;   // safe address; value masked below
        float v = partial[(size_t)b * S_ + t];
        lg[l] = valid ? v : Lc;
    }
    float m = lg[0];
    #pragma unroll
    for (int l = 1; l < LCK; ++l) m = fmaxf(m, lg[l]);
    float denom = 0.f;
    #pragma unroll
    for (int l = 0; l < LCK; ++l) { lg[l] = expf(lg[l] - m); denom += lg[l]; }
    float inv = 1.0f / denom;

    // weighted sum over valid tokens (invalid x-rows are zero in the reference)
    const float* Xb = X + (size_t)b * S_ * D_;
    float o[3];
    float sum = 0.f, sq = 0.f;
    #pragma unroll
    for (int kk = 0; kk < 3; ++kk) {
        int d = tid + kk * 256;
        float s = 0.f;
        for (int l = 0; l < len; ++l)
            s += lg[l] * Xb[(size_t)(start + l) * D_ + d];
        s *= inv;
        o[kk] = s;
        sum += s;
        sq += s * s;
    }

    // block reduction for mean / var (4 waves of 64)
    #pragma unroll
    for (int off = 32; off > 0; off >>= 1) {
        sum += __shfl_down(sum, off);
        sq  += __shfl_down(sq, off);
    }
    __shared__ float rs[4], rq[4];
    int lane = tid & 63, wid = tid >> 6;
    if (lane == 0) { rs[wid] = sum; rq[wid] = sq; }
    __syncthreads();
    float tot  = rs[0] + rs[1] + rs[2] + rs[3];
    float totq = rq[0] + rq[1] + rq[2] + rq[3];
    float u = tot * (1.0f / D_);
    float var = totq * (1.0f / D_) - u * u;
    var = fmaxf(var, 0.0f);
    float rstd = rsqrtf(var + 1e-12f);

    float* out = cf + ((size_t)b * C_ + c) * D_;
    #pragma unroll
    for (int kk = 0; kk < 3; ++kk) {
        int d = tid + kk * 256;
        out[d] = lnw[d] * ((o[kk] - u) * rstd) + lnb[d];
    }
}

// ---------------- Kernel 4: sentence_embedding = max over 128 chunks ----------------
__global__ __launch_bounds__(256) void max_kernel(const float* __restrict__ cf,
                                                  float* __restrict__ sent) {
    int b = blockIdx.x;
    int d = blockIdx.y * 256 + threadIdx.x;
    const float* p = cf + (size_t)b * C_ * D_ + d;
    float m = -INFINITY;
    #pragma unroll 8
    for (int c = 0; c < C_; ++c) m = fmaxf(m, p[(size_t)c * D_]);
    sent[(size_t)b * D_ + d] = m;
}

extern "C" void kernel_launch(void* const* d_in, const int* in_sizes, int n_in,
                              void* d_out, int out_size, void* d_ws, size_t ws_size,
                              hipStream_t stream) {
    const float* X   = (const float*)d_in[0];  // tokens (32,512,768)
    const int*   ln_ = (const int*)d_in[1];    // chunk_lens (32,128)
    const float* W   = (const float*)d_in[2];  // dense_w (768,768)
    const float* db  = (const float*)d_in[3];  // dense_b (768)
    const float* ab  = (const float*)d_in[4];  // attn_bias (768)
    const float* q   = (const float*)d_in[5];  // query (768)
    const float* lnw = (const float*)d_in[6];  // ln_w (768)
    const float* lnb = (const float*)d_in[7];  // ln_b (768)

    float* cf   = (float*)d_out;                       // (32,128,768)
    float* sent = cf + (size_t)B_ * C_ * D_;           // (32,768)

    // workspace layout (all 16B-aligned), total ~2.46 MB
    int*      starts  = (int*)d_ws;                                   // 16 KB
    int*      Tb      = (int*)((char*)d_ws + 16384);                  // 128 B
    float*    Lc      = (float*)((char*)d_ws + 16640);                // 4 B
    _Float16* Whf     = (_Float16*)((char*)d_ws + 32768);             // 1.125 MB
    _Float16* Wlf     = (_Float16*)((char*)d_ws + 32768 + 1179648);   // 1.125 MB
    float*    partial = (float*)((char*)d_ws + 32768 + 2 * 1179648);  // 32*512*4 = 64 KB

    scan_lc_kernel<<<33, 256, 0, stream>>>(ln_, starts, Tb, db, ab, q, Lc);
    wsplit_kernel<<<(D_ * D_) / (256 * 4), 256, 0, stream>>>(W, Whf, Wlf);

    dim3 g2(S_ / 64 * 2 - 4, B_);   // 12 m-tiles of 32 rows (Tb <= 384)
    logits_mfma<<<g2, 256, 0, stream>>>(X, Whf, Wlf, db, ab, q, Tb, partial);

    dim3 g3(C_, B_);
    chunk_kernel<<<g3, 256, 0, stream>>>(X, ln_, starts, partial, Lc, lnw, lnb, cf);
    dim3 g4(B_, 3);
    max_kernel<<<g4, 256, 0, stream>>>(cf, sent);
}